// Round 1
// baseline (445.915 us; speedup 1.0000x reference)
//
#include <hip/hip_runtime.h>
#include <math.h>

#define NN 512
#define NC 3

// Radial cutoff envelope e[i][j] = (r<4.5)/r, r=sqrt((i+1)^2+(j+1)^2), i,j in 0..3
__device__ __constant__ float d_env[16] = {
    0.70710678f, 0.44721360f, 0.31622777f, 0.24253563f,
    0.44721360f, 0.35355339f, 0.27735010f, 0.22360680f,
    0.31622777f, 0.27735010f, 0.23570226f, 0.00000000f,
    0.24253563f, 0.22360680f, 0.00000000f, 0.00000000f
};

// One thread = 4 consecutive x pixels of one (b,y) row, all 3 channels.
// Block of 256 threads = 2 rows (128 threads x 4 px = 512 px per row).
__global__ __launch_bounds__(256) void diffeo_kernel(
    const float* __restrict__ xin,
    const float* __restrict__ Fx,
    const float* __restrict__ Fy,
    float* __restrict__ out,
    float scale)
{
    const int tid  = threadIdx.x;
    const int row  = blockIdx.x * 2 + (tid >> 7);   // [0, 64*512)
    const int lane = tid & 127;
    const int b    = row >> 9;
    const int y    = row & (NN - 1);
    const int x0   = lane << 2;

    // per-row sine table sy[j] = sin(pi * y/511 * (j+1))
    const float ys = (float)y * (1.0f / 511.0f);
    float sy[4];
#pragma unroll
    for (int j = 0; j < 4; ++j)
        sy[j] = sinf((float)M_PI * ys * (float)(j + 1));

    // fold F*e*sy over j: gu[i] = sum_j Fx[b,i,j]*e[i,j]*sy[j]  (same for gv with Fy)
    const float* fx = Fx + b * 16;
    const float* fy = Fy + b * 16;
    float gu[4], gv[4];
#pragma unroll
    for (int i = 0; i < 4; ++i) {
        float su = 0.0f, sv = 0.0f;
#pragma unroll
        for (int j = 0; j < 4; ++j) {
            const float w = d_env[i * 4 + j] * sy[j];
            su += fx[i * 4 + j] * w;
            sv += fy[i * 4 + j] * w;
        }
        gu[i] = su;
        gv[i] = sv;
    }

    const float* __restrict__ base = xin + (size_t)b * NC * NN * NN;
    float outv[NC][4];

#pragma unroll
    for (int p = 0; p < 4; ++p) {
        const int xx = x0 + p;
        const float xs = (float)xx * (1.0f / 511.0f);
        float u = 0.0f, v = 0.0f;
#pragma unroll
        for (int i = 0; i < 4; ++i) {
            const float sx = sinf((float)M_PI * xs * (float)(i + 1));
            u += sx * gu[i];
            v += sx * gv[i];
        }
        // xn = clip(x - scale*u, 0, 511); yn = clip(y - scale*v, 0, 511)
        const float xn = fminf(fmaxf((float)xx - scale * u, 0.0f), 511.0f);
        const float yn = fminf(fmaxf((float)y  - scale * v, 0.0f), 511.0f);
        const float xff = floorf(xn), yff = floorf(yn);
        const int xf = (int)xff,        yf = (int)yff;
        const int xc = (int)ceilf(xn),  yc = (int)ceilf(yn);
        const float xv = xn - xff, yv = yn - yff;

        const int o00 = yf * NN + xf;
        const int o01 = yf * NN + xc;
        const int o10 = yc * NN + xf;
        const int o11 = yc * NN + xc;

#pragma unroll
        for (int c = 0; c < NC; ++c) {
            const float* img = base + (size_t)c * NN * NN;
            const float v00 = img[o00];
            const float v01 = img[o01];
            const float v10 = img[o10];
            const float v11 = img[o11];
            const float top = v00 + xv * (v01 - v00);
            const float bot = v10 + xv * (v11 - v10);
            outv[c][p] = top + yv * (bot - top);
        }
    }

    // coalesced float4 stores, one per channel
#pragma unroll
    for (int c = 0; c < NC; ++c) {
        float4 o = make_float4(outv[c][0], outv[c][1], outv[c][2], outv[c][3]);
        *(float4*)(out + (((size_t)b * NC + c) * NN + y) * NN + x0) = o;
    }
}

extern "C" void kernel_launch(void* const* d_in, const int* in_sizes, int n_in,
                              void* d_out, int out_size, void* d_ws, size_t ws_size,
                              hipStream_t stream) {
    const float* x  = (const float*)d_in[0];
    const float* Fx = (const float*)d_in[1];
    const float* Fy = (const float*)d_in[2];
    float* out = (float*)d_out;

    // typ = n * sqrt(pi*log(cut)) / 2 ; scale = sqrt(T/typ^2) * n
    const double typ = 512.0 * sqrt(M_PI * log(4.0)) / 2.0;
    const float scale = (float)(sqrt(0.01 / (typ * typ)) * 512.0);

    // 64*512 rows, 2 rows per block
    diffeo_kernel<<<64 * 512 / 2, 256, 0, stream>>>(x, Fx, Fy, out, scale);
}

// Round 2
// 438.784 us; speedup vs baseline: 1.0163x; 1.0163x over previous
//
#include <hip/hip_runtime.h>
#include <math.h>

#define NN 512
#define NC 3

// Radial cutoff envelope e[i][j] = (r<4.5)/r, r=sqrt((i+1)^2+(j+1)^2), i,j in 0..3
__device__ __constant__ float d_env[16] = {
    0.70710678f, 0.44721360f, 0.31622777f, 0.24253563f,
    0.44721360f, 0.35355339f, 0.27735010f, 0.22360680f,
    0.31622777f, 0.27735010f, 0.23570226f, 0.00000000f,
    0.24253563f, 0.22360680f, 0.00000000f, 0.00000000f
};

// Sine table in d_ws:
//   tabX[i][p] at ws[i*512 + p]      (i-major: float4 over p, 16B aligned for p%4==0)
//   tabY[p][j] at ws[2048 + p*4 + j] (p-major: one float4 per row)
// Both hold S(p,k) = sin(pi * p * (k+1) / 511).
__global__ __launch_bounds__(256) void sine_table_kernel(float* __restrict__ ws) {
    const int t = blockIdx.x * 256 + threadIdx.x;   // 2048 threads
    const int j = t & 3;
    const int p = t >> 2;
    const float val = sinf((float)M_PI * (float)p * (1.0f / 511.0f) * (float)(j + 1));
    ws[2048 + t] = val;           // tabY[p][j]
    ws[j * 512 + p] = val;        // tabX[j][p]
}

// One thread = 4 consecutive x pixels of one (b,y) row, all 3 channels.
// Block of 256 threads = 2 rows; 256 blocks per batch -> b = blockIdx>>8 (scalar).
__global__ __launch_bounds__(256) void diffeo_kernel(
    const float* __restrict__ xin,
    const float* __restrict__ Fx,
    const float* __restrict__ Fy,
    float* __restrict__ out,
    const float* __restrict__ ws,
    float scale)
{
    const int tid = threadIdx.x;
    const int b   = blockIdx.x >> 8;                      // wave-uniform
    const int y   = ((blockIdx.x << 1) + (tid >> 7)) & (NN - 1);
    const int x0  = (tid & 127) << 2;

    // per-row sine vector sy[j] from table (one float4 load)
    const float4 sy = *(const float4*)(ws + 2048 + y * 4);
    const float syv[4] = { sy.x, sy.y, sy.z, sy.w };

    // fold F*e*sy over j, scale included: cu[i] = scale * sum_j F[b,i,j]*e[i,j]*sy[j]
    const float* fx = Fx + b * 16;
    const float* fy = Fy + b * 16;
    float cu[4], cv[4];
#pragma unroll
    for (int i = 0; i < 4; ++i) {
        float su = 0.0f, sv = 0.0f;
#pragma unroll
        for (int j = 0; j < 4; ++j) {
            const float w = d_env[i * 4 + j] * syv[j];
            su += fx[i * 4 + j] * w;
            sv += fy[i * 4 + j] * w;
        }
        cu[i] = scale * su;
        cv[i] = scale * sv;
    }

    // sx[i] for this thread's 4 pixels: 4 aligned float4 loads
    float sxv[4][4];
#pragma unroll
    for (int i = 0; i < 4; ++i) {
        const float4 s = *(const float4*)(ws + i * 512 + x0);
        sxv[i][0] = s.x; sxv[i][1] = s.y; sxv[i][2] = s.z; sxv[i][3] = s.w;
    }

    const float* __restrict__ base = xin + (size_t)b * NC * NN * NN;
    float outv[NC][4];

#pragma unroll
    for (int p = 0; p < 4; ++p) {
        const int xx = x0 + p;
        float du = 0.0f, dv = 0.0f;
#pragma unroll
        for (int i = 0; i < 4; ++i) {
            du += sxv[i][p] * cu[i];
            dv += sxv[i][p] * cv[i];
        }
        const float xn = fminf(fmaxf((float)xx - du, 0.0f), 511.0f);
        const float yn = fminf(fmaxf((float)y  - dv, 0.0f), 511.0f);
        const float xff = floorf(xn), yff = floorf(yn);
        const int xf = (int)xff,        yf = (int)yff;
        const int xc = (int)ceilf(xn),  yc = (int)ceilf(yn);
        const float xv = xn - xff, yv = yn - yff;

        const int o00 = yf * NN + xf;
        const int o01 = yf * NN + xc;
        const int o10 = yc * NN + xf;
        const int o11 = yc * NN + xc;

#pragma unroll
        for (int c = 0; c < NC; ++c) {
            const float* img = base + (size_t)c * NN * NN;
            const float v00 = img[o00];
            const float v01 = img[o01];
            const float v10 = img[o10];
            const float v11 = img[o11];
            const float top = v00 + xv * (v01 - v00);
            const float bot = v10 + xv * (v11 - v10);
            outv[c][p] = top + yv * (bot - top);
        }
    }

#pragma unroll
    for (int c = 0; c < NC; ++c) {
        float4 o = make_float4(outv[c][0], outv[c][1], outv[c][2], outv[c][3]);
        *(float4*)(out + (((size_t)b * NC + c) * NN + y) * NN + x0) = o;
    }
}

extern "C" void kernel_launch(void* const* d_in, const int* in_sizes, int n_in,
                              void* d_out, int out_size, void* d_ws, size_t ws_size,
                              hipStream_t stream) {
    const float* x  = (const float*)d_in[0];
    const float* Fx = (const float*)d_in[1];
    const float* Fy = (const float*)d_in[2];
    float* out = (float*)d_out;
    float* ws  = (float*)d_ws;   // 16 KB sine tables (re-built every call; ws re-poisoned)

    // typ = n * sqrt(pi*log(cut)) / 2 ; scale = sqrt(T/typ^2) * n
    const double typ = 512.0 * sqrt(M_PI * log(4.0)) / 2.0;
    const float scale = (float)(sqrt(0.01 / (typ * typ)) * 512.0);

    sine_table_kernel<<<8, 256, 0, stream>>>(ws);
    diffeo_kernel<<<64 * 512 / 2, 256, 0, stream>>>(x, Fx, Fy, out, ws, scale);
}